// Round 3
// baseline (793.339 us; speedup 1.0000x reference)
//
#include <hip/hip_runtime.h>
#include <stdint.h>

#define BATCH   512
#define NFEAT   128
#define EWORDS  64     // E = 2048 bits -> 64 uint32 words
#define HSIZE   8192
#define HWORDS  256    // 8192 bits -> 256 uint32 words
#define NCLS    10
#define THRESH_I 4
#define CAP     128    // max sparse entries per row (mean ~32); -1 => dense

// ---------------------------------------------------------------------------
// Encode: thermometer bits of x into bit matrix act0[word][batch].
// Also zeroes outAcc and the pad ("always zero") word of each act buffer,
// used by sentinel entries that pad sparse lists to a multiple of 8.
// ---------------------------------------------------------------------------
__global__ __launch_bounds__(256) void encode_kernel(
    const float* __restrict__ x,
    uint32_t* __restrict__ act0, uint32_t* __restrict__ act1,
    uint32_t* __restrict__ act2, uint32_t* __restrict__ act3,
    float* __restrict__ outAcc) {
  int t = blockIdx.x * 256 + threadIdx.x;        // 32768 threads
  if (t < BATCH * NCLS) outAcc[t] = 0.0f;
  if (t < BATCH) {
    act0[EWORDS * BATCH + t] = 0u;               // pad words (sentinel target)
    act1[HWORDS * BATCH + t] = 0u;
    act2[HWORDS * BATCH + t] = 0u;
    act3[HWORDS * BATCH + t] = 0u;
  }
  int b = t >> 6;          // batch
  int w = t & 63;          // word index
  if (b < BATCH) {
    float u0 = x[b * NFEAT + 2 * w] * 16.0f;
    float u1 = x[b * NFEAT + 2 * w + 1] * 16.0f;
    uint32_t word = 0;
#pragma unroll
    for (int j = 0; j < 16; ++j) {
      word |= (u0 > (float)j ? 1u : 0u) << j;
      word |= (u1 > (float)j ? 1u : 0u) << (16 + j);
    }
    act0[w * BATCH + b] = word;
  }
}

// ---------------------------------------------------------------------------
// Convert: stream W rows (dense f32 in {-1,0,+1}) -> packed sparse lists.
// Entry = (elem_index << 1) | (w < 0). One wave per row; coalesced float4
// stream with manual double-buffer; ballot compaction. Lists padded to a
// multiple of 8 with sentinel entries (e = P -> zeroed pad word).
// counts[row] = padded count, or -1 => dense fallback (never in practice).
// W2 rows are handled by the same launch when row >= rows0 (fused stream).
// ---------------------------------------------------------------------------
template <int P>
__global__ __launch_bounds__(256, 8) void convert_kernel(
    const float* __restrict__ WA, const float* __restrict__ WB, int rows0,
    uint32_t* __restrict__ lists, int* __restrict__ counts) {
  int wid = (blockIdx.x * 256 + threadIdx.x) >> 6;   // global wave = row
  int lane = threadIdx.x & 63;
  const float* W = (wid < rows0) ? WA : WB;
  int row = (wid < rows0) ? wid : wid - rows0;
  constexpr int NIT = P / 256;                       // 256 elems per wave-load

  const float4* w4 = (const float4*)(W + (size_t)row * P);
  uint32_t* lp = lists + (size_t)wid * CAP;
  uint64_t lmask = (lane == 63) ? ~0ull : ((1ull << (lane + 1)) - 1ull);
  lmask >>= 1;  // bits strictly below lane... (avoid 1<<64)
  // simpler: lmask = bits below lane
  lmask = (lane == 0) ? 0ull : (~0ull >> (64 - lane));

  int cnt = 0;
  float4 cur = w4[lane];
  for (int it = 0; it < NIT; ++it) {
    float4 nxt;
    if (it + 1 < NIT) nxt = w4[(it + 1) * 64 + lane];
    int eb = it * 256 + lane * 4;
#pragma unroll
    for (int k = 0; k < 4; ++k) {
      float v = (k == 0) ? cur.x : (k == 1) ? cur.y : (k == 2) ? cur.z : cur.w;
      uint64_t m = __ballot(v != 0.0f);
      if (m) {
        int pos = (int)__popcll(m & lmask);
        if (v != 0.0f && cnt + pos < CAP) {
          lp[cnt + pos] = (uint32_t)((eb + k) << 1) | (v < 0.0f ? 1u : 0u);
        }
        cnt += (int)__popcll(m);
      }
    }
    cur = nxt;
  }
  // pad to multiple of 8 with sentinel entries (e = P -> zero pad word)
  int pad = (8 - (cnt & 7)) & 7;
  if (lane < pad && cnt + lane < CAP) lp[cnt + lane] = (uint32_t)(P << 1);
  int total = cnt + pad;
  if (lane == 0) counts[wid] = (total <= CAP) ? total : -1;
}

// ---------------------------------------------------------------------------
// Dense-fallback helper (only runs if a row overflowed CAP; correctness net).
// ---------------------------------------------------------------------------
__device__ __forceinline__ void proc_comp(float v, int ebase,
                                          const uint32_t* __restrict__ actIn,
                                          int lane, int* z) {
  uint64_t m = __ballot(v != 0.0f);
  if (m == 0ull) return;
  uint64_t pm = __ballot(v > 0.0f);
  do {
    uint32_t src = (uint32_t)__builtin_ctzll(m);
    m &= m - 1;
    int e = ebase + 4 * (int)src;
    const uint4* aw =
        (const uint4*)(actIn + (size_t)(e >> 5) * BATCH + lane * 8);
    uint4 a0 = aw[0];
    uint4 a1 = aw[1];
    uint32_t sh = (uint32_t)(e & 31);
    int s = ((pm >> src) & 1ull) ? 1 : -1;
    z[0] += s * (int)((a0.x >> sh) & 1u);
    z[1] += s * (int)((a0.y >> sh) & 1u);
    z[2] += s * (int)((a0.z >> sh) & 1u);
    z[3] += s * (int)((a0.w >> sh) & 1u);
    z[4] += s * (int)((a1.x >> sh) & 1u);
    z[5] += s * (int)((a1.y >> sh) & 1u);
    z[6] += s * (int)((a1.z >> sh) & 1u);
    z[7] += s * (int)((a1.w >> sh) & 1u);
  } while (m);
}

// ---------------------------------------------------------------------------
// Sparse layer: per row, walk the packed entry list in blocks of 8 (16
// independent uint4 act loads in flight); threshold -> bit matrix.
// Block = 512 threads (8 waves), 2 rows/wave -> 16 rows/block (uint16 half).
// ---------------------------------------------------------------------------
__device__ __forceinline__ void proc_ent(uint32_t ent,
                                         const uint32_t* __restrict__ actIn,
                                         int lane, int* z) {
  uint32_t negm = (uint32_t)(-(int)(ent & 1u));
  int ee = (int)(ent >> 1);
  const uint4* aw =
      (const uint4*)(actIn + (size_t)(ee >> 5) * BATCH + lane * 8);
  uint4 a0 = aw[0];
  uint4 a1 = aw[1];
  uint32_t sh = (uint32_t)(ee & 31);
  uint32_t t;
  t = (a0.x >> sh) & 1u; z[0] += (int)((t ^ negm) - negm);
  t = (a0.y >> sh) & 1u; z[1] += (int)((t ^ negm) - negm);
  t = (a0.z >> sh) & 1u; z[2] += (int)((t ^ negm) - negm);
  t = (a0.w >> sh) & 1u; z[3] += (int)((t ^ negm) - negm);
  t = (a1.x >> sh) & 1u; z[4] += (int)((t ^ negm) - negm);
  t = (a1.y >> sh) & 1u; z[5] += (int)((t ^ negm) - negm);
  t = (a1.z >> sh) & 1u; z[6] += (int)((t ^ negm) - negm);
  t = (a1.w >> sh) & 1u; z[7] += (int)((t ^ negm) - negm);
}

template <int P>
__global__ __launch_bounds__(512, 4) void layer_kernel(
    const uint32_t* __restrict__ lists, const int* __restrict__ counts,
    const float* __restrict__ W,
    const uint32_t* __restrict__ actIn,
    uint32_t* __restrict__ actOut) {
  __shared__ uint32_t shOut[BATCH];
  int tid = threadIdx.x;
  shOut[tid] = 0u;
  __syncthreads();

  int wave = tid >> 6;
  int lane = tid & 63;
  int hbase = blockIdx.x * 16;

  for (int r = 0; r < 2; ++r) {
    int h = hbase + wave * 2 + r;
    int z[8];
#pragma unroll
    for (int i = 0; i < 8; ++i) z[i] = 0;

    int cnt = counts[h];
    if (cnt >= 0) {
      const uint32_t* lp = lists + (size_t)h * CAP;
      for (int i = 0; i < cnt; i += 8) {
        uint4 eA = *(const uint4*)(lp + i);
        uint4 eB = *(const uint4*)(lp + i + 4);
        proc_ent(eA.x, actIn, lane, z);
        proc_ent(eA.y, actIn, lane, z);
        proc_ent(eA.z, actIn, lane, z);
        proc_ent(eA.w, actIn, lane, z);
        proc_ent(eB.x, actIn, lane, z);
        proc_ent(eB.y, actIn, lane, z);
        proc_ent(eB.z, actIn, lane, z);
        proc_ent(eB.w, actIn, lane, z);
      }
    } else {
      // dense fallback (CAP overflow; effectively never taken)
      const float4* wrow = (const float4*)(W + (size_t)h * P) + lane;
      for (int it = 0; it < P / 256; ++it) {
        float4 wv = wrow[it * 64];
        int eb = it * 256;
        proc_comp(wv.x, eb + 0, actIn, lane, z);
        proc_comp(wv.y, eb + 1, actIn, lane, z);
        proc_comp(wv.z, eb + 2, actIn, lane, z);
        proc_comp(wv.w, eb + 3, actIn, lane, z);
      }
    }

    uint32_t bitm = 1u << (h & 15);
#pragma unroll
    for (int i = 0; i < 8; ++i) {
      if (z[i] >= THRESH_I) atomicOr(&shOut[lane * 8 + i], bitm);
    }
  }
  __syncthreads();
  int word = (int)(blockIdx.x >> 1);
  int half = (int)(blockIdx.x & 1);
  ((uint16_t*)actOut)[(size_t)word * (BATCH * 2) + tid * 2 + half] =
      (uint16_t)shOut[tid];
}

// ---------------------------------------------------------------------------
// Output accumulation with LDS-staged outConn chunk (256 rows, padded to 12).
// Grid: 96 chunks x 8 batch-groups = 768 blocks of 256 threads.
// ---------------------------------------------------------------------------
#define CHUNK 256
__global__ __launch_bounds__(256, 4) void outacc_kernel(
    const float* __restrict__ outConn,
    const uint32_t* __restrict__ ab1,
    const uint32_t* __restrict__ ab2,
    const uint32_t* __restrict__ ab3,
    float* __restrict__ outAcc) {
  __shared__ float shOC[CHUNK][12];
  int tid = threadIdx.x;
  int bg = blockIdx.x & 7;
  int chunk = blockIdx.x >> 3;                     // 0..95
  int gbase = chunk * CHUNK;                       // global row base

  for (int idx = tid; idx < CHUNK * NCLS; idx += 256) {
    int r = idx / NCLS;
    int c = idx - r * NCLS;
    shOC[r][c] = outConn[(size_t)gbase * NCLS + idx];
  }
  __syncthreads();

  int wave = tid >> 6;
  int lane = tid & 63;
  int b = bg * 64 + lane;
  int layer = gbase >> 13;
  const uint32_t* ab = (layer == 0) ? ab1 : (layer == 1) ? ab2 : ab3;

  float acc[NCLS];
#pragma unroll
  for (int c = 0; c < NCLS; ++c) acc[c] = 0.0f;

  int rbase = wave * 64;                           // rows within chunk
  for (int k = 0; k < 2; ++k) {
    int rr = rbase + k * 32;
    int h = (gbase & (HSIZE - 1)) + rr;
    uint32_t wbits = ab[(size_t)(h >> 5) * BATCH + b];
    for (int j = 0; j < 32; ++j) {
      float bitf = (float)((wbits >> j) & 1u);
      const float* oc = shOC[rr + j];
#pragma unroll
      for (int c = 0; c < NCLS; ++c) acc[c] += bitf * oc[c];
    }
  }
#pragma unroll
  for (int c = 0; c < NCLS; ++c) {
    atomicAdd(&outAcc[b * NCLS + c], acc[c]);
  }
}

// ---------------------------------------------------------------------------
// Final: argmax per batch; write preds (int32) then outAct (f32) into d_out.
// ---------------------------------------------------------------------------
__global__ __launch_bounds__(256) void final_kernel(
    const float* __restrict__ outAcc,
    int* __restrict__ preds,
    float* __restrict__ outF) {
  int b = blockIdx.x * 256 + threadIdx.x;
  if (b < BATCH) {
    float vals[NCLS];
#pragma unroll
    for (int c = 0; c < NCLS; ++c) vals[c] = outAcc[b * NCLS + c];
    float best = vals[0];
    int bi = 0;
#pragma unroll
    for (int c = 1; c < NCLS; ++c) {
      if (vals[c] > best) { best = vals[c]; bi = c; }
    }
    preds[b] = bi;
#pragma unroll
    for (int c = 0; c < NCLS; ++c) outF[b * NCLS + c] = vals[c];
  }
}

extern "C" void kernel_launch(void* const* d_in, const int* in_sizes, int n_in,
                              void* d_out, int out_size, void* d_ws, size_t ws_size,
                              hipStream_t stream) {
  const float* x       = (const float*)d_in[1];
  const float* W0      = (const float*)d_in[2];
  const float* W1      = (const float*)d_in[3];
  const float* W2      = (const float*)d_in[4];
  const float* outConn = (const float*)d_in[5];

  uint32_t* ws   = (uint32_t*)d_ws;
  uint32_t* act0 = ws;                               // (64+1)*512 words
  uint32_t* act1 = act0 + (EWORDS + 1) * BATCH;      // (256+1)*512 words
  uint32_t* act2 = act1 + (HWORDS + 1) * BATCH;
  uint32_t* act3 = act2 + (HWORDS + 1) * BATCH;
  uint32_t* lists0  = act3 + (HWORDS + 1) * BATCH;   // 8192*CAP
  uint32_t* lists12 = lists0 + (size_t)HSIZE * CAP;  // 16384*CAP
  int* counts0  = (int*)(lists12 + (size_t)2 * HSIZE * CAP);
  int* counts12 = counts0 + HSIZE;
  float* outAcc = (float*)(counts12 + 2 * HSIZE);

  encode_kernel<<<128, 256, 0, stream>>>(x, act0, act1, act2, act3, outAcc);
  convert_kernel<2048><<<HSIZE / 4, 256, 0, stream>>>(
      W0, W0, HSIZE, lists0, counts0);
  convert_kernel<8192><<<2 * HSIZE / 4, 256, 0, stream>>>(
      W1, W2, HSIZE, lists12, counts12);
  layer_kernel<2048><<<HSIZE / 16, 512, 0, stream>>>(
      lists0, counts0, W0, act0, act1);
  layer_kernel<8192><<<HSIZE / 16, 512, 0, stream>>>(
      lists12, counts12, W1, act1, act2);
  layer_kernel<8192><<<HSIZE / 16, 512, 0, stream>>>(
      lists12 + (size_t)HSIZE * CAP, counts12 + HSIZE, W2, act2, act3);
  outacc_kernel<<<768, 256, 0, stream>>>(outConn, act1, act2, act3, outAcc);
  final_kernel<<<2, 256, 0, stream>>>(outAcc, (int*)d_out,
                                      (float*)d_out + BATCH);
}

// Round 4
// 659.288 us; speedup vs baseline: 1.2033x; 1.2033x over previous
//
#include <hip/hip_runtime.h>
#include <stdint.h>

#define BATCH   512
#define NFEAT   128
#define ESIZE   2048   // encoded feature size (bits)
#define HSIZE   8192
#define NCLS    10
#define THRESH_I 4
#define CAP     128    // max sparse entries per row (mean ~32); -1 => dense
#define ROWB    64     // bytes per bit-plane row (512 batches / 8)

// Bit-plane layout: actT[h] is 64 bytes; byte beta, bit i  <->  batch beta+64*i.

// ---------------------------------------------------------------------------
// Encode: one wave per feature f; lane beta handles batches beta+64i.
// Produces actT0 rows e = f*16 + j. Also zeroes outAcc and the pad row of
// each bit-plane buffer (sentinel target for padded entry lists).
// ---------------------------------------------------------------------------
__global__ __launch_bounds__(256) void encode_kernel(
    const float* __restrict__ x,
    uint8_t* __restrict__ aT0, uint8_t* __restrict__ aT1,
    uint8_t* __restrict__ aT2, uint8_t* __restrict__ aT3,
    float* __restrict__ outAcc) {
  int t = blockIdx.x * 256 + threadIdx.x;        // 8192 threads
  if (t < BATCH * NCLS) outAcc[t] = 0.0f;
  else if (t < 5120 + 64)  aT0[(size_t)ESIZE * ROWB + (t - 5120)] = 0;
  else if (t < 5184 + 64)  aT1[(size_t)HSIZE * ROWB + (t - 5184)] = 0;
  else if (t < 5248 + 64)  aT2[(size_t)HSIZE * ROWB + (t - 5248)] = 0;
  else if (t < 5312 + 64)  aT3[(size_t)HSIZE * ROWB + (t - 5312)] = 0;

  int wave = threadIdx.x >> 6;
  int lane = threadIdx.x & 63;
  int f = blockIdx.x * 4 + wave;
  if (f < NFEAT) {
    float u[8];
#pragma unroll
    for (int i = 0; i < 8; ++i)
      u[i] = x[(size_t)(lane + 64 * i) * NFEAT + f] * 16.0f;
#pragma unroll
    for (int j = 0; j < 16; ++j) {
      uint32_t byte = 0;
#pragma unroll
      for (int i = 0; i < 8; ++i)
        byte |= (u[i] > (float)j ? 1u : 0u) << i;
      aT0[(size_t)(f * 16 + j) * ROWB + lane] = (uint8_t)byte;
    }
  }
}

// ---------------------------------------------------------------------------
// Convert (fused W0+W1+W2): stream W rows -> packed sparse entry lists.
// Entry = (elem_index << 1) | (w<0). One wave per row; 512 elems/iteration
// with one-deep double buffer (2 KB in flight). Short dependency chain:
// 8 independent ballots, prefix adds, one cnt update per iteration.
// Lists padded to multiple of 8 with sentinel e=P (zeroed pad row).
// ---------------------------------------------------------------------------
__global__ __launch_bounds__(256, 8) void convert_kernel(
    const float* __restrict__ W0, const float* __restrict__ W1,
    const float* __restrict__ W2,
    uint32_t* __restrict__ lists, int* __restrict__ counts) {
  int wid = (blockIdx.x * 256 + threadIdx.x) >> 6;   // global wave = row
  int lane = threadIdx.x & 63;
  const float* W;
  int row, P;
  if (wid < HSIZE)            { W = W0; row = wid;             P = ESIZE; }
  else if (wid < 2 * HSIZE)   { W = W1; row = wid - HSIZE;     P = HSIZE; }
  else                        { W = W2; row = wid - 2 * HSIZE; P = HSIZE; }

  const float4* w4 = (const float4*)(W + (size_t)row * P);
  uint32_t* lp = lists + (size_t)wid * CAP;
  uint64_t lmask = (lane == 0) ? 0ull : (~0ull >> (64 - lane));
  int nit = P >> 9;                                  // 512 elems per iter
  int cnt = 0;
  float4 c0 = w4[lane];
  float4 c1 = w4[64 + lane];

  for (int it = 0; it < nit; ++it) {
    float4 n0, n1;
    bool more = (it + 1 < nit);
    if (more) {
      n0 = w4[(it + 1) * 128 + lane];
      n1 = w4[(it + 1) * 128 + 64 + lane];
    }
    float v[8] = {c0.x, c0.y, c0.z, c0.w, c1.x, c1.y, c1.z, c1.w};
    uint64_t m[8];
    int tt[8];
#pragma unroll
    for (int k = 0; k < 8; ++k) {
      m[k] = __ballot(v[k] != 0.0f);
      tt[k] = (int)__popcll(m[k]);
    }
    int off = cnt;
#pragma unroll
    for (int k = 0; k < 8; ++k) {
      if (v[k] != 0.0f) {
        int pos = off + (int)__popcll(m[k] & lmask);
        int e = it * 512 + (k >> 2) * 256 + (k & 3) + lane * 4;
        if (pos < CAP)
          lp[pos] = ((uint32_t)e << 1) | (v[k] < 0.0f ? 1u : 0u);
      }
      off += tt[k];
    }
    cnt = off;
    if (more) { c0 = n0; c1 = n1; }
  }
  int pad = (8 - (cnt & 7)) & 7;
  if (lane < pad && cnt + lane < CAP) lp[cnt + lane] = (uint32_t)(P << 1);
  if (lane == 0) counts[wid] = (cnt + pad <= CAP) ? (cnt + pad) : -1;
}

// ---------------------------------------------------------------------------
// Sparse layer on bit-plane layout: per entry, lane loads ONE byte (the 8
// batches it owns) -> 64 B per wave per entry. Output = direct byte store.
// ---------------------------------------------------------------------------
__device__ __forceinline__ void proc_ent(uint32_t ent,
                                         const uint8_t* __restrict__ aIn,
                                         int lane, int* z) {
  uint32_t negm = (uint32_t)(-(int)(ent & 1u));
  uint32_t ee = ent >> 1;
  uint32_t byte = (uint32_t)aIn[(size_t)ee * ROWB + lane];
#pragma unroll
  for (int i = 0; i < 8; ++i) {
    uint32_t t = (byte >> i) & 1u;
    z[i] += (int)((t ^ negm) - negm);
  }
}

__device__ __forceinline__ void proc_comp_dense(float v, int ebase,
                                                const uint8_t* __restrict__ aIn,
                                                int lane, int* z) {
  uint64_t m = __ballot(v != 0.0f);
  if (m == 0ull) return;
  uint64_t pm = __ballot(v > 0.0f);
  do {
    uint32_t src = (uint32_t)__builtin_ctzll(m);
    m &= m - 1;
    int e = ebase + 4 * (int)src;
    uint32_t negm = ((pm >> src) & 1ull) ? 0u : 0xFFFFFFFFu;
    uint32_t byte = (uint32_t)aIn[(size_t)e * ROWB + lane];
#pragma unroll
    for (int i = 0; i < 8; ++i) {
      uint32_t t = (byte >> i) & 1u;
      z[i] += (int)((t ^ negm) - negm);
    }
  } while (m);
}

template <int P>
__global__ __launch_bounds__(512, 4) void layer_kernel(
    const uint32_t* __restrict__ lists, const int* __restrict__ counts,
    const float* __restrict__ W,
    const uint8_t* __restrict__ aIn, uint8_t* __restrict__ aOut) {
  int wave = threadIdx.x >> 6;
  int lane = threadIdx.x & 63;
  int hbase = blockIdx.x * 16 + wave * 2;

  for (int r = 0; r < 2; ++r) {
    int h = hbase + r;
    int z[8];
#pragma unroll
    for (int i = 0; i < 8; ++i) z[i] = 0;

    int cnt = counts[h];
    if (cnt >= 0) {
      const uint32_t* lp = lists + (size_t)h * CAP;
      if (cnt > 0) {
        uint4 eA = *(const uint4*)(lp);
        uint4 eB = *(const uint4*)(lp + 4);
        for (int i = 0; i < cnt; i += 8) {
          // prefetch next group (may read a few words past this row's slot;
          // stays inside the workspace -> harmless)
          uint4 nA = *(const uint4*)(lp + i + 8);
          uint4 nB = *(const uint4*)(lp + i + 12);
          proc_ent(eA.x, aIn, lane, z);
          proc_ent(eA.y, aIn, lane, z);
          proc_ent(eA.z, aIn, lane, z);
          proc_ent(eA.w, aIn, lane, z);
          proc_ent(eB.x, aIn, lane, z);
          proc_ent(eB.y, aIn, lane, z);
          proc_ent(eB.z, aIn, lane, z);
          proc_ent(eB.w, aIn, lane, z);
          eA = nA;
          eB = nB;
        }
      }
    } else {
      // dense fallback (CAP overflow; effectively never taken)
      const float4* wrow = (const float4*)(W + (size_t)h * P) + lane;
      for (int it = 0; it < P / 256; ++it) {
        float4 wv = wrow[it * 64];
        int eb = it * 256;
        proc_comp_dense(wv.x, eb + 0, aIn, lane, z);
        proc_comp_dense(wv.y, eb + 1, aIn, lane, z);
        proc_comp_dense(wv.z, eb + 2, aIn, lane, z);
        proc_comp_dense(wv.w, eb + 3, aIn, lane, z);
      }
    }

    uint32_t ob = 0;
#pragma unroll
    for (int i = 0; i < 8; ++i)
      ob |= (z[i] >= THRESH_I ? 1u : 0u) << i;
    aOut[(size_t)h * ROWB + lane] = (uint8_t)ob;
  }
}

// ---------------------------------------------------------------------------
// Output accumulation on bit planes. Chunk of 128 rows per block; outConn
// chunk staged in LDS; per-thread acc[8][10]; LDS reduce (batch-strided
// mapping -> 4-way banks); ~1M global atomics total.
// ---------------------------------------------------------------------------
#define OCHUNK 128
__global__ __launch_bounds__(256, 4) void outacc_kernel(
    const float* __restrict__ outConn,
    const uint8_t* __restrict__ a1, const uint8_t* __restrict__ a2,
    const uint8_t* __restrict__ a3,
    float* __restrict__ outAcc) {
  __shared__ float shOC[OCHUNK][NCLS];
  __shared__ float shAcc[BATCH * NCLS];
  int tid = threadIdx.x;
  int gbase = blockIdx.x * OCHUNK;                 // 0..24448
  for (int idx = tid; idx < OCHUNK * NCLS; idx += 256)
    ((float*)shOC)[idx] = outConn[(size_t)gbase * NCLS + idx];
  for (int idx = tid; idx < BATCH * NCLS; idx += 256) shAcc[idx] = 0.0f;
  __syncthreads();

  int wave = tid >> 6;
  int lane = tid & 63;
  int layer = gbase >> 13;
  const uint8_t* aT = (layer == 0) ? a1 : (layer == 1) ? a2 : a3;
  int h0 = (gbase & (HSIZE - 1)) + wave * 32;

  float acc[8][NCLS];
#pragma unroll
  for (int i = 0; i < 8; ++i)
#pragma unroll
    for (int c = 0; c < NCLS; ++c) acc[i][c] = 0.0f;

  for (int r = 0; r < 32; ++r) {
    int row = h0 + r;
    uint32_t byte = (uint32_t)aT[(size_t)row * ROWB + lane];
    float bf[8];
#pragma unroll
    for (int i = 0; i < 8; ++i) bf[i] = (float)((byte >> i) & 1u);
    const float* oc = shOC[wave * 32 + r];
#pragma unroll
    for (int c = 0; c < NCLS; ++c) {
      float o = oc[c];
#pragma unroll
      for (int i = 0; i < 8; ++i) acc[i][c] += bf[i] * o;
    }
  }
#pragma unroll
  for (int i = 0; i < 8; ++i)
#pragma unroll
    for (int c = 0; c < NCLS; ++c)
      atomicAdd(&shAcc[(size_t)(lane + 64 * i) * NCLS + c], acc[i][c]);
  __syncthreads();
  for (int idx = tid; idx < BATCH * NCLS; idx += 256)
    atomicAdd(&outAcc[idx], shAcc[idx]);
}

// ---------------------------------------------------------------------------
// Final: argmax per batch; write preds (int32) then outAct (f32) into d_out.
// ---------------------------------------------------------------------------
__global__ __launch_bounds__(256) void final_kernel(
    const float* __restrict__ outAcc,
    int* __restrict__ preds,
    float* __restrict__ outF) {
  int b = blockIdx.x * 256 + threadIdx.x;
  if (b < BATCH) {
    float vals[NCLS];
#pragma unroll
    for (int c = 0; c < NCLS; ++c) vals[c] = outAcc[b * NCLS + c];
    float best = vals[0];
    int bi = 0;
#pragma unroll
    for (int c = 1; c < NCLS; ++c) {
      if (vals[c] > best) { best = vals[c]; bi = c; }
    }
    preds[b] = bi;
#pragma unroll
    for (int c = 0; c < NCLS; ++c) outF[b * NCLS + c] = vals[c];
  }
}

extern "C" void kernel_launch(void* const* d_in, const int* in_sizes, int n_in,
                              void* d_out, int out_size, void* d_ws, size_t ws_size,
                              hipStream_t stream) {
  const float* x       = (const float*)d_in[1];
  const float* W0      = (const float*)d_in[2];
  const float* W1      = (const float*)d_in[3];
  const float* W2      = (const float*)d_in[4];
  const float* outConn = (const float*)d_in[5];

  uint8_t* base = (uint8_t*)d_ws;
  uint8_t* aT0 = base;                               // (2048+1)*64 B
  uint8_t* aT1 = base + 0x40000;                     // (8192+1)*64 B each
  uint8_t* aT2 = aT1 + 0x90000;
  uint8_t* aT3 = aT2 + 0x90000;
  uint32_t* lists = (uint32_t*)(aT3 + 0x90000);      // 24576*CAP words
  int* counts = (int*)((uint8_t*)lists + (size_t)3 * HSIZE * CAP * 4);
  float* outAcc = (float*)(counts + 3 * HSIZE);

  encode_kernel<<<32, 256, 0, stream>>>(x, aT0, aT1, aT2, aT3, outAcc);
  convert_kernel<<<6144, 256, 0, stream>>>(W0, W1, W2, lists, counts);
  layer_kernel<ESIZE><<<512, 512, 0, stream>>>(
      lists, counts, W0, aT0, aT1);
  layer_kernel<HSIZE><<<512, 512, 0, stream>>>(
      lists + (size_t)HSIZE * CAP, counts + HSIZE, W1, aT1, aT2);
  layer_kernel<HSIZE><<<512, 512, 0, stream>>>(
      lists + (size_t)2 * HSIZE * CAP, counts + 2 * HSIZE, W2, aT2, aT3);
  outacc_kernel<<<192, 256, 0, stream>>>(outConn, aT1, aT2, aT3, outAcc);
  final_kernel<<<2, 256, 0, stream>>>(outAcc, (int*)d_out,
                                      (float*)d_out + BATCH);
}

// Round 5
// 656.987 us; speedup vs baseline: 1.2075x; 1.0035x over previous
//
#include <hip/hip_runtime.h>
#include <stdint.h>

#define BATCH   512
#define NFEAT   128
#define ESIZE   2048   // encoded feature size (bits)
#define HSIZE   8192
#define NCLS    10
#define THRESH_I 4
#define CAP     128    // max sparse entries per row (mean ~32); -1 => dense
#define ROWB    64     // bytes per bit-plane row (512 batches / 8)

// Bit-plane layout: actT[h] is 64 bytes; byte beta, bit i  <->  batch beta+64*i.

// ---------------------------------------------------------------------------
// Encode: one wave per feature f; lane beta handles batches beta+64i.
// Produces actT0 rows e = f*16 + j. Also zeroes outAcc and the pad row of
// each bit-plane buffer (sentinel target for padded entry lists).
// ---------------------------------------------------------------------------
__global__ __launch_bounds__(256) void encode_kernel(
    const float* __restrict__ x,
    uint8_t* __restrict__ aT0, uint8_t* __restrict__ aT1,
    uint8_t* __restrict__ aT2, uint8_t* __restrict__ aT3,
    float* __restrict__ outAcc) {
  int t = blockIdx.x * 256 + threadIdx.x;        // 8192 threads
  if (t < BATCH * NCLS) outAcc[t] = 0.0f;
  else if (t < 5120 + 64)  aT0[(size_t)ESIZE * ROWB + (t - 5120)] = 0;
  else if (t < 5184 + 64)  aT1[(size_t)HSIZE * ROWB + (t - 5184)] = 0;
  else if (t < 5248 + 64)  aT2[(size_t)HSIZE * ROWB + (t - 5248)] = 0;
  else if (t < 5312 + 64)  aT3[(size_t)HSIZE * ROWB + (t - 5312)] = 0;

  int wave = threadIdx.x >> 6;
  int lane = threadIdx.x & 63;
  int f = blockIdx.x * 4 + wave;
  if (f < NFEAT) {
    float u[8];
#pragma unroll
    for (int i = 0; i < 8; ++i)
      u[i] = x[(size_t)(lane + 64 * i) * NFEAT + f] * 16.0f;
#pragma unroll
    for (int j = 0; j < 16; ++j) {
      uint32_t byte = 0;
#pragma unroll
      for (int i = 0; i < 8; ++i)
        byte |= (u[i] > (float)j ? 1u : 0u) << i;
      aT0[(size_t)(f * 16 + j) * ROWB + lane] = (uint8_t)byte;
    }
  }
}

// ---------------------------------------------------------------------------
// Convert (fused W0+W1+W2): stream W rows -> packed sparse entry lists.
// Entry = (elem_index << 1) | (w<0). One wave per row.
// Key structure: entries buffered in LDS (lgkmcnt domain) so the global
// vmcnt chain holds ONLY the stream loads; rotating 2-deep register
// prefetch (no copies -> no per-iteration vmcnt(0) drain). One coalesced
// global flush per row at the end.
// ---------------------------------------------------------------------------
__device__ __forceinline__ void cvt_proc(float4 c0, float4 c1, int it,
                                         int lane, uint64_t lmask,
                                         uint32_t* __restrict__ shw,
                                         int& cnt) {
  float v[8] = {c0.x, c0.y, c0.z, c0.w, c1.x, c1.y, c1.z, c1.w};
  uint64_t m[8];
  int tt[8];
#pragma unroll
  for (int k = 0; k < 8; ++k) {
    m[k] = __ballot(v[k] != 0.0f);
    tt[k] = (int)__popcll(m[k]);
  }
  int off = cnt;
#pragma unroll
  for (int k = 0; k < 8; ++k) {
    if (v[k] != 0.0f) {
      int pos = off + (int)__popcll(m[k] & lmask);
      int e = it * 512 + (k >> 2) * 256 + (k & 3) + lane * 4;
      if (pos < CAP)
        shw[pos] = ((uint32_t)e << 1) | (v[k] < 0.0f ? 1u : 0u);
    }
    off += tt[k];
  }
  cnt = off;
}

__global__ __launch_bounds__(256, 8) void convert_kernel(
    const float* __restrict__ W0, const float* __restrict__ W1,
    const float* __restrict__ W2,
    uint32_t* __restrict__ lists, int* __restrict__ counts) {
  __shared__ uint32_t shEnt[4][CAP];
  int wave = threadIdx.x >> 6;
  int lane = threadIdx.x & 63;
  int wid = blockIdx.x * 4 + wave;                   // global wave = row
  const float* W;
  int row, P;
  if (wid < HSIZE)            { W = W0; row = wid;             P = ESIZE; }
  else if (wid < 2 * HSIZE)   { W = W1; row = wid - HSIZE;     P = HSIZE; }
  else                        { W = W2; row = wid - 2 * HSIZE; P = HSIZE; }

  const float4* w4 = (const float4*)(W + (size_t)row * P);
  uint32_t* shw = shEnt[wave];
  uint64_t lmask = (lane == 0) ? 0ull : (~0ull >> (64 - lane));
  int nit = P >> 9;                                  // 512 elems per iter (4|16)
  int cnt = 0;

  // rotating 2-deep prefetch, unroll-by-2 (nit is even)
  float4 a0 = w4[lane];
  float4 a1 = w4[64 + lane];
  float4 b0 = w4[128 + lane];
  float4 b1 = w4[192 + lane];

  for (int it = 0; it < nit; it += 2) {
    cvt_proc(a0, a1, it, lane, lmask, shw, cnt);
    if (it + 2 < nit) {
      a0 = w4[(it + 2) * 128 + lane];
      a1 = w4[(it + 2) * 128 + 64 + lane];
    }
    cvt_proc(b0, b1, it + 1, lane, lmask, shw, cnt);
    if (it + 3 < nit) {
      b0 = w4[(it + 3) * 128 + lane];
      b1 = w4[(it + 3) * 128 + 64 + lane];
    }
  }

  // pad to multiple of 8 with sentinel entries (e = P -> zeroed pad row)
  int pad = (8 - (cnt & 7)) & 7;
  if (lane < pad && cnt + lane < CAP) shw[cnt + lane] = (uint32_t)(P << 1);
  int total = cnt + pad;
  int wtotal = (total <= CAP) ? total : CAP;
  // same-wave LDS write->read; compiler inserts lgkmcnt wait, no barrier
  uint32_t* lp = lists + (size_t)wid * CAP;
  for (int i = lane; i < wtotal; i += 64) lp[i] = shw[i];
  if (lane == 0) counts[wid] = (total <= CAP) ? total : -1;
}

// ---------------------------------------------------------------------------
// Sparse layer on bit-plane layout: per entry, lane loads ONE byte (the 8
// batches it owns) -> 64 B per wave per entry. Output = direct byte store.
// ---------------------------------------------------------------------------
__device__ __forceinline__ void proc_ent(uint32_t ent,
                                         const uint8_t* __restrict__ aIn,
                                         int lane, int* z) {
  uint32_t negm = (uint32_t)(-(int)(ent & 1u));
  uint32_t ee = ent >> 1;
  uint32_t byte = (uint32_t)aIn[(size_t)ee * ROWB + lane];
#pragma unroll
  for (int i = 0; i < 8; ++i) {
    uint32_t t = (byte >> i) & 1u;
    z[i] += (int)((t ^ negm) - negm);
  }
}

__device__ __forceinline__ void proc_comp_dense(float v, int ebase,
                                                const uint8_t* __restrict__ aIn,
                                                int lane, int* z) {
  uint64_t m = __ballot(v != 0.0f);
  if (m == 0ull) return;
  uint64_t pm = __ballot(v > 0.0f);
  do {
    uint32_t src = (uint32_t)__builtin_ctzll(m);
    m &= m - 1;
    int e = ebase + 4 * (int)src;
    uint32_t negm = ((pm >> src) & 1ull) ? 0u : 0xFFFFFFFFu;
    uint32_t byte = (uint32_t)aIn[(size_t)e * ROWB + lane];
#pragma unroll
    for (int i = 0; i < 8; ++i) {
      uint32_t t = (byte >> i) & 1u;
      z[i] += (int)((t ^ negm) - negm);
    }
  } while (m);
}

template <int P>
__global__ __launch_bounds__(512, 4) void layer_kernel(
    const uint32_t* __restrict__ lists, const int* __restrict__ counts,
    const float* __restrict__ W,
    const uint8_t* __restrict__ aIn, uint8_t* __restrict__ aOut) {
  int wave = threadIdx.x >> 6;
  int lane = threadIdx.x & 63;
  int hbase = blockIdx.x * 16 + wave * 2;

  for (int r = 0; r < 2; ++r) {
    int h = hbase + r;
    int z[8];
#pragma unroll
    for (int i = 0; i < 8; ++i) z[i] = 0;

    int cnt = counts[h];
    if (cnt >= 0) {
      const uint32_t* lp = lists + (size_t)h * CAP;
      if (cnt > 0) {
        uint4 eA = *(const uint4*)(lp);
        uint4 eB = *(const uint4*)(lp + 4);
        for (int i = 0; i < cnt; i += 8) {
          // prefetch next group (may read a few words past this row's slot;
          // stays inside the workspace -> harmless)
          uint4 nA = *(const uint4*)(lp + i + 8);
          uint4 nB = *(const uint4*)(lp + i + 12);
          proc_ent(eA.x, aIn, lane, z);
          proc_ent(eA.y, aIn, lane, z);
          proc_ent(eA.z, aIn, lane, z);
          proc_ent(eA.w, aIn, lane, z);
          proc_ent(eB.x, aIn, lane, z);
          proc_ent(eB.y, aIn, lane, z);
          proc_ent(eB.z, aIn, lane, z);
          proc_ent(eB.w, aIn, lane, z);
          eA = nA;
          eB = nB;
        }
      }
    } else {
      // dense fallback (CAP overflow; effectively never taken)
      const float4* wrow = (const float4*)(W + (size_t)h * P) + lane;
      for (int it = 0; it < P / 256; ++it) {
        float4 wv = wrow[it * 64];
        int eb = it * 256;
        proc_comp_dense(wv.x, eb + 0, aIn, lane, z);
        proc_comp_dense(wv.y, eb + 1, aIn, lane, z);
        proc_comp_dense(wv.z, eb + 2, aIn, lane, z);
        proc_comp_dense(wv.w, eb + 3, aIn, lane, z);
      }
    }

    uint32_t ob = 0;
#pragma unroll
    for (int i = 0; i < 8; ++i)
      ob |= (z[i] >= THRESH_I ? 1u : 0u) << i;
    aOut[(size_t)h * ROWB + lane] = (uint8_t)ob;
  }
}

// ---------------------------------------------------------------------------
// Output accumulation on bit planes. Chunk of 128 rows per block; outConn
// chunk staged in LDS; per-thread acc[8][10]; LDS reduce then global atomics.
// ---------------------------------------------------------------------------
#define OCHUNK 128
__global__ __launch_bounds__(256, 4) void outacc_kernel(
    const float* __restrict__ outConn,
    const uint8_t* __restrict__ a1, const uint8_t* __restrict__ a2,
    const uint8_t* __restrict__ a3,
    float* __restrict__ outAcc) {
  __shared__ float shOC[OCHUNK][NCLS];
  __shared__ float shAcc[BATCH * NCLS];
  int tid = threadIdx.x;
  int gbase = blockIdx.x * OCHUNK;                 // 0..24448
  for (int idx = tid; idx < OCHUNK * NCLS; idx += 256)
    ((float*)shOC)[idx] = outConn[(size_t)gbase * NCLS + idx];
  for (int idx = tid; idx < BATCH * NCLS; idx += 256) shAcc[idx] = 0.0f;
  __syncthreads();

  int wave = tid >> 6;
  int lane = tid & 63;
  int layer = gbase >> 13;
  const uint8_t* aT = (layer == 0) ? a1 : (layer == 1) ? a2 : a3;
  int h0 = (gbase & (HSIZE - 1)) + wave * 32;

  float acc[8][NCLS];
#pragma unroll
  for (int i = 0; i < 8; ++i)
#pragma unroll
    for (int c = 0; c < NCLS; ++c) acc[i][c] = 0.0f;

  for (int r = 0; r < 32; ++r) {
    int row = h0 + r;
    uint32_t byte = (uint32_t)aT[(size_t)row * ROWB + lane];
    float bf[8];
#pragma unroll
    for (int i = 0; i < 8; ++i) bf[i] = (float)((byte >> i) & 1u);
    const float* oc = shOC[wave * 32 + r];
#pragma unroll
    for (int c = 0; c < NCLS; ++c) {
      float o = oc[c];
#pragma unroll
      for (int i = 0; i < 8; ++i) acc[i][c] += bf[i] * o;
    }
  }
#pragma unroll
  for (int i = 0; i < 8; ++i)
#pragma unroll
    for (int c = 0; c < NCLS; ++c)
      atomicAdd(&shAcc[(size_t)(lane + 64 * i) * NCLS + c], acc[i][c]);
  __syncthreads();
  for (int idx = tid; idx < BATCH * NCLS; idx += 256)
    atomicAdd(&outAcc[idx], shAcc[idx]);
}

// ---------------------------------------------------------------------------
// Final: argmax per batch; write preds (int32) then outAct (f32) into d_out.
// ---------------------------------------------------------------------------
__global__ __launch_bounds__(256) void final_kernel(
    const float* __restrict__ outAcc,
    int* __restrict__ preds,
    float* __restrict__ outF) {
  int b = blockIdx.x * 256 + threadIdx.x;
  if (b < BATCH) {
    float vals[NCLS];
#pragma unroll
    for (int c = 0; c < NCLS; ++c) vals[c] = outAcc[b * NCLS + c];
    float best = vals[0];
    int bi = 0;
#pragma unroll
    for (int c = 1; c < NCLS; ++c) {
      if (vals[c] > best) { best = vals[c]; bi = c; }
    }
    preds[b] = bi;
#pragma unroll
    for (int c = 0; c < NCLS; ++c) outF[b * NCLS + c] = vals[c];
  }
}

extern "C" void kernel_launch(void* const* d_in, const int* in_sizes, int n_in,
                              void* d_out, int out_size, void* d_ws, size_t ws_size,
                              hipStream_t stream) {
  const float* x       = (const float*)d_in[1];
  const float* W0      = (const float*)d_in[2];
  const float* W1      = (const float*)d_in[3];
  const float* W2      = (const float*)d_in[4];
  const float* outConn = (const float*)d_in[5];

  uint8_t* base = (uint8_t*)d_ws;
  uint8_t* aT0 = base;                               // (2048+1)*64 B
  uint8_t* aT1 = base + 0x40000;                     // (8192+1)*64 B each
  uint8_t* aT2 = aT1 + 0x90000;
  uint8_t* aT3 = aT2 + 0x90000;
  uint32_t* lists = (uint32_t*)(aT3 + 0x90000);      // 24576*CAP words
  int* counts = (int*)((uint8_t*)lists + (size_t)3 * HSIZE * CAP * 4);
  float* outAcc = (float*)(counts + 3 * HSIZE);

  encode_kernel<<<32, 256, 0, stream>>>(x, aT0, aT1, aT2, aT3, outAcc);
  convert_kernel<<<6144, 256, 0, stream>>>(W0, W1, W2, lists, counts);
  layer_kernel<ESIZE><<<512, 512, 0, stream>>>(
      lists, counts, W0, aT0, aT1);
  layer_kernel<HSIZE><<<512, 512, 0, stream>>>(
      lists + (size_t)HSIZE * CAP, counts + HSIZE, W1, aT1, aT2);
  layer_kernel<HSIZE><<<512, 512, 0, stream>>>(
      lists + (size_t)2 * HSIZE * CAP, counts + 2 * HSIZE, W2, aT2, aT3);
  outacc_kernel<<<192, 256, 0, stream>>>(outConn, aT1, aT2, aT3, outAcc);
  final_kernel<<<2, 256, 0, stream>>>(outAcc, (int*)d_out,
                                      (float*)d_out + BATCH);
}

// Round 6
// 651.373 us; speedup vs baseline: 1.2179x; 1.0086x over previous
//
#include <hip/hip_runtime.h>
#include <stdint.h>

#define BATCH   512
#define NFEAT   128
#define ESIZE   2048   // encoded feature size (bits)
#define HSIZE   8192
#define NCLS    10
#define THRESH_I 4
#define CAP     128    // max sparse entries per row (mean ~32); > CAP => dense
#define ROWB    64     // bytes per bit-plane row (512 batches / 8)

// Bit-plane layout: actT[h] is 64 bytes; byte beta, bit i  <->  batch beta+64*i.

// ---------------------------------------------------------------------------
// Encode: one wave per feature f; lane beta handles batches beta+64i.
// Produces actT0 rows e = f*16 + j. Also zeroes outAcc, the pad row of each
// bit-plane buffer (sentinel target), and the counts array for convert.
// ---------------------------------------------------------------------------
__global__ __launch_bounds__(256) void encode_kernel(
    const float* __restrict__ x,
    uint8_t* __restrict__ aT0, uint8_t* __restrict__ aT1,
    uint8_t* __restrict__ aT2, uint8_t* __restrict__ aT3,
    int* __restrict__ counts,
    float* __restrict__ outAcc) {
  int t = blockIdx.x * 256 + threadIdx.x;        // 8192 threads
  if (t < BATCH * NCLS) outAcc[t] = 0.0f;
  else if (t < 5120 + 64)  aT0[(size_t)ESIZE * ROWB + (t - 5120)] = 0;
  else if (t < 5184 + 64)  aT1[(size_t)HSIZE * ROWB + (t - 5184)] = 0;
  else if (t < 5248 + 64)  aT2[(size_t)HSIZE * ROWB + (t - 5248)] = 0;
  else if (t < 5312 + 64)  aT3[(size_t)HSIZE * ROWB + (t - 5312)] = 0;
  counts[t] = 0;
  counts[t + 8192] = 0;
  counts[t + 16384] = 0;

  int wave = threadIdx.x >> 6;
  int lane = threadIdx.x & 63;
  int f = blockIdx.x * 4 + wave;
  if (f < NFEAT) {
    float u[8];
#pragma unroll
    for (int i = 0; i < 8; ++i)
      u[i] = x[(size_t)(lane + 64 * i) * NFEAT + f] * 16.0f;
#pragma unroll
    for (int j = 0; j < 16; ++j) {
      uint32_t byte = 0;
#pragma unroll
      for (int i = 0; i < 8; ++i)
        byte |= (u[i] > (float)j ? 1u : 0u) << i;
      aT0[(size_t)(f * 16 + j) * ROWB + lane] = (uint8_t)byte;
    }
  }
}

// ---------------------------------------------------------------------------
// Convert (stripe-parallel, fused W0+W1+W2): one wave per 1024-element
// contiguous stripe-pair (never crosses a row). Issue 4 float4 loads, one
// wait, 16 ballots, ONE atomicAdd on counts[row] to reserve slots, scatter
// the few entries, exit. No per-wave loop, no serial cnt chain — the read
// stream advances at dispatch rate like a fill/copy kernel.
// Entry = (elem_index << 1) | (w<0). counts end EXACT (no padding).
// ---------------------------------------------------------------------------
__global__ __launch_bounds__(256, 8) void convert_kernel(
    const float* __restrict__ W0, const float* __restrict__ W1,
    const float* __restrict__ W2,
    uint32_t* __restrict__ lists, int* __restrict__ counts) {
  int pair = (blockIdx.x * 256 + threadIdx.x) >> 6;  // global wave id
  int lane = threadIdx.x & 63;

  // region decode (wave-uniform): W0 = 16384 pairs, W1/W2 = 65536 each
  const float* W;
  int row, sloc, wid, P;
  if (pair < 16384) {
    W = W0; P = ESIZE;
    int s0 = pair * 2;
    row = s0 >> 2; sloc = s0 & 3; wid = row;
  } else if (pair < 16384 + 65536) {
    W = W1; P = HSIZE;
    int s0 = (pair - 16384) * 2;
    row = s0 >> 4; sloc = s0 & 15; wid = HSIZE + row;
  } else {
    W = W2; P = HSIZE;
    int s0 = (pair - 16384 - 65536) * 2;
    row = s0 >> 4; sloc = s0 & 15; wid = 2 * HSIZE + row;
  }

  const float4* w4 = (const float4*)(W + (size_t)row * P + (size_t)sloc * 512);
  float4 c0 = w4[lane];
  float4 c1 = w4[64 + lane];
  float4 c2 = w4[128 + lane];
  float4 c3 = w4[192 + lane];

  float v[16] = {c0.x, c0.y, c0.z, c0.w, c1.x, c1.y, c1.z, c1.w,
                 c2.x, c2.y, c2.z, c2.w, c3.x, c3.y, c3.z, c3.w};
  uint64_t m[16];
  int tt[16];
#pragma unroll
  for (int k = 0; k < 16; ++k) {
    m[k] = __ballot(v[k] != 0.0f);
    tt[k] = (int)__popcll(m[k]);
  }
  int total = 0;
#pragma unroll
  for (int k = 0; k < 16; ++k) total += tt[k];
  if (total == 0) return;                            // wave-uniform early out

  int base = 0;
  if (lane == 0) base = atomicAdd(&counts[wid], total);
  base = __shfl(base, 0);

  uint64_t lmask = (lane == 0) ? 0ull : (~0ull >> (64 - lane));
  int ebase = sloc * 512;
  uint32_t* lp = lists + (size_t)wid * CAP;
  int off = base;
#pragma unroll
  for (int k = 0; k < 16; ++k) {
    if (v[k] != 0.0f) {
      int pos = off + (int)__popcll(m[k] & lmask);
      // elem = ebase + quarter*256 + 4*lane + (k&3)
      int e = ebase + (k >> 2) * 256 + (k & 3) + lane * 4;
      if (pos < CAP)
        lp[pos] = ((uint32_t)e << 1) | (v[k] < 0.0f ? 1u : 0u);
    }
    off += tt[k];
  }
}

// ---------------------------------------------------------------------------
// Sparse layer on bit-plane layout: per entry, lane loads ONE byte (the 8
// batches it owns) -> 64 B per wave per entry. Output = direct byte store.
// Tail group masked with sentinel e=P (zeroed pad row).
// ---------------------------------------------------------------------------
__device__ __forceinline__ void proc_ent(uint32_t ent,
                                         const uint8_t* __restrict__ aIn,
                                         int lane, int* z) {
  uint32_t negm = (uint32_t)(-(int)(ent & 1u));
  uint32_t ee = ent >> 1;
  uint32_t byte = (uint32_t)aIn[(size_t)ee * ROWB + lane];
#pragma unroll
  for (int i = 0; i < 8; ++i) {
    uint32_t t = (byte >> i) & 1u;
    z[i] += (int)((t ^ negm) - negm);
  }
}

__device__ __forceinline__ void proc_comp_dense(float v, int ebase,
                                                const uint8_t* __restrict__ aIn,
                                                int lane, int* z) {
  uint64_t m = __ballot(v != 0.0f);
  if (m == 0ull) return;
  uint64_t pm = __ballot(v > 0.0f);
  do {
    uint32_t src = (uint32_t)__builtin_ctzll(m);
    m &= m - 1;
    int e = ebase + 4 * (int)src;
    uint32_t negm = ((pm >> src) & 1ull) ? 0u : 0xFFFFFFFFu;
    uint32_t byte = (uint32_t)aIn[(size_t)e * ROWB + lane];
#pragma unroll
    for (int i = 0; i < 8; ++i) {
      uint32_t t = (byte >> i) & 1u;
      z[i] += (int)((t ^ negm) - negm);
    }
  } while (m);
}

template <int P>
__global__ __launch_bounds__(512, 4) void layer_kernel(
    const uint32_t* __restrict__ lists, const int* __restrict__ counts,
    const float* __restrict__ W,
    const uint8_t* __restrict__ aIn, uint8_t* __restrict__ aOut) {
  int wave = threadIdx.x >> 6;
  int lane = threadIdx.x & 63;
  int hbase = blockIdx.x * 16 + wave * 2;
  const uint32_t SENT = (uint32_t)(P << 1);

  for (int r = 0; r < 2; ++r) {
    int h = hbase + r;
    int z[8];
#pragma unroll
    for (int i = 0; i < 8; ++i) z[i] = 0;

    int cnt = counts[h];
    if (cnt <= CAP) {
      const uint32_t* lp = lists + (size_t)h * CAP;
      int full = cnt & ~7;
      for (int i = 0; i < full; i += 8) {
        uint4 eA = *(const uint4*)(lp + i);
        uint4 eB = *(const uint4*)(lp + i + 4);
        proc_ent(eA.x, aIn, lane, z);
        proc_ent(eA.y, aIn, lane, z);
        proc_ent(eA.z, aIn, lane, z);
        proc_ent(eA.w, aIn, lane, z);
        proc_ent(eB.x, aIn, lane, z);
        proc_ent(eB.y, aIn, lane, z);
        proc_ent(eB.z, aIn, lane, z);
        proc_ent(eB.w, aIn, lane, z);
      }
      if (cnt & 7) {
        // tail: load the 8-group (slack allocated), mask beyond cnt
        uint4 eA = *(const uint4*)(lp + full);
        uint4 eB = *(const uint4*)(lp + full + 4);
        uint32_t ee[8] = {eA.x, eA.y, eA.z, eA.w, eB.x, eB.y, eB.z, eB.w};
#pragma unroll
        for (int j = 0; j < 8; ++j)
          ee[j] = (full + j < cnt) ? ee[j] : SENT;
#pragma unroll
        for (int j = 0; j < 8; ++j) proc_ent(ee[j], aIn, lane, z);
      }
    } else {
      // dense fallback (CAP overflow; effectively never taken)
      const float4* wrow = (const float4*)(W + (size_t)h * P) + lane;
      for (int it = 0; it < P / 256; ++it) {
        float4 wv = wrow[it * 64];
        int eb = it * 256;
        proc_comp_dense(wv.x, eb + 0, aIn, lane, z);
        proc_comp_dense(wv.y, eb + 1, aIn, lane, z);
        proc_comp_dense(wv.z, eb + 2, aIn, lane, z);
        proc_comp_dense(wv.w, eb + 3, aIn, lane, z);
      }
    }

    uint32_t ob = 0;
#pragma unroll
    for (int i = 0; i < 8; ++i)
      ob |= (z[i] >= THRESH_I ? 1u : 0u) << i;
    aOut[(size_t)h * ROWB + lane] = (uint8_t)ob;
  }
}

// ---------------------------------------------------------------------------
// Output accumulation on bit planes. Chunk of 128 rows per block; outConn
// chunk staged in LDS; per-thread acc[8][10]; LDS reduce then global atomics.
// ---------------------------------------------------------------------------
#define OCHUNK 128
__global__ __launch_bounds__(256, 4) void outacc_kernel(
    const float* __restrict__ outConn,
    const uint8_t* __restrict__ a1, const uint8_t* __restrict__ a2,
    const uint8_t* __restrict__ a3,
    float* __restrict__ outAcc) {
  __shared__ float shOC[OCHUNK][NCLS];
  __shared__ float shAcc[BATCH * NCLS];
  int tid = threadIdx.x;
  int gbase = blockIdx.x * OCHUNK;                 // 0..24448
  for (int idx = tid; idx < OCHUNK * NCLS; idx += 256)
    ((float*)shOC)[idx] = outConn[(size_t)gbase * NCLS + idx];
  for (int idx = tid; idx < BATCH * NCLS; idx += 256) shAcc[idx] = 0.0f;
  __syncthreads();

  int wave = tid >> 6;
  int lane = tid & 63;
  int layer = gbase >> 13;
  const uint8_t* aT = (layer == 0) ? a1 : (layer == 1) ? a2 : a3;
  int h0 = (gbase & (HSIZE - 1)) + wave * 32;

  float acc[8][NCLS];
#pragma unroll
  for (int i = 0; i < 8; ++i)
#pragma unroll
    for (int c = 0; c < NCLS; ++c) acc[i][c] = 0.0f;

  for (int r = 0; r < 32; ++r) {
    int row = h0 + r;
    uint32_t byte = (uint32_t)aT[(size_t)row * ROWB + lane];
    float bf[8];
#pragma unroll
    for (int i = 0; i < 8; ++i) bf[i] = (float)((byte >> i) & 1u);
    const float* oc = shOC[wave * 32 + r];
#pragma unroll
    for (int c = 0; c < NCLS; ++c) {
      float o = oc[c];
#pragma unroll
      for (int i = 0; i < 8; ++i) acc[i][c] += bf[i] * o;
    }
  }
#pragma unroll
  for (int i = 0; i < 8; ++i)
#pragma unroll
    for (int c = 0; c < NCLS; ++c)
      atomicAdd(&shAcc[(size_t)(lane + 64 * i) * NCLS + c], acc[i][c]);
  __syncthreads();
  for (int idx = tid; idx < BATCH * NCLS; idx += 256)
    atomicAdd(&outAcc[idx], shAcc[idx]);
}

// ---------------------------------------------------------------------------
// Final: argmax per batch; write preds (int32) then outAct (f32) into d_out.
// ---------------------------------------------------------------------------
__global__ __launch_bounds__(256) void final_kernel(
    const float* __restrict__ outAcc,
    int* __restrict__ preds,
    float* __restrict__ outF) {
  int b = blockIdx.x * 256 + threadIdx.x;
  if (b < BATCH) {
    float vals[NCLS];
#pragma unroll
    for (int c = 0; c < NCLS; ++c) vals[c] = outAcc[b * NCLS + c];
    float best = vals[0];
    int bi = 0;
#pragma unroll
    for (int c = 1; c < NCLS; ++c) {
      if (vals[c] > best) { best = vals[c]; bi = c; }
    }
    preds[b] = bi;
#pragma unroll
    for (int c = 0; c < NCLS; ++c) outF[b * NCLS + c] = vals[c];
  }
}

extern "C" void kernel_launch(void* const* d_in, const int* in_sizes, int n_in,
                              void* d_out, int out_size, void* d_ws, size_t ws_size,
                              hipStream_t stream) {
  const float* x       = (const float*)d_in[1];
  const float* W0      = (const float*)d_in[2];
  const float* W1      = (const float*)d_in[3];
  const float* W2      = (const float*)d_in[4];
  const float* outConn = (const float*)d_in[5];

  uint8_t* base = (uint8_t*)d_ws;
  uint8_t* aT0 = base;                               // (2048+1)*64 B
  uint8_t* aT1 = base + 0x40000;                     // (8192+1)*64 B each
  uint8_t* aT2 = aT1 + 0x90000;
  uint8_t* aT3 = aT2 + 0x90000;
  uint32_t* lists = (uint32_t*)(aT3 + 0x90000);      // 24576*CAP words (+slack)
  int* counts = (int*)((uint8_t*)lists +
                       ((size_t)3 * HSIZE * CAP + 64) * 4);
  float* outAcc = (float*)(counts + 3 * HSIZE);

  encode_kernel<<<32, 256, 0, stream>>>(x, aT0, aT1, aT2, aT3, counts, outAcc);
  // 147456 stripe-pairs -> 36864 blocks of 256 (4 waves/block)
  convert_kernel<<<36864, 256, 0, stream>>>(W0, W1, W2, lists, counts);
  layer_kernel<ESIZE><<<512, 512, 0, stream>>>(
      lists, counts, W0, aT0, aT1);
  layer_kernel<HSIZE><<<512, 512, 0, stream>>>(
      lists + (size_t)HSIZE * CAP, counts + HSIZE, W1, aT1, aT2);
  layer_kernel<HSIZE><<<512, 512, 0, stream>>>(
      lists + (size_t)2 * HSIZE * CAP, counts + 2 * HSIZE, W2, aT2, aT3);
  outacc_kernel<<<192, 256, 0, stream>>>(outConn, aT1, aT2, aT3, outAcc);
  final_kernel<<<2, 256, 0, stream>>>(outAcc, (int*)d_out,
                                      (float*)d_out + BATCH);
}